// Round 1
// baseline (419.838 us; speedup 1.0000x reference)
//
#include <hip/hip_runtime.h>

#define NCAM 6
#define CCH  128
#define IH   64
#define IW   176
#define NQ   640000           // 200*200*16
#define PIX  (IH * IW)        // 11264 = 352*32
#define QT   64               // queries per block
#define LSTRIDE 129           // odd LDS stride: phase-C q-major reads are 2-way (free)

typedef float f32x2 __attribute__((ext_vector_type(2)));
typedef float f32x4 __attribute__((ext_vector_type(4)));

// ---------------------------------------------------------------------------
// Kernel 1: transpose img_feats (cam, c, y, x) -> (cam, y, x, c). ~15 us.
// Source reads are single-use -> non-temporal (evict-first), keep L2/L3 for
// the transposed copy which the gather kernel re-reads ~9.5x per line.
// ---------------------------------------------------------------------------
__global__ __launch_bounds__(256) void transpose_kernel(
    const float* __restrict__ in, float* __restrict__ out) {
    __shared__ float tile[32][33];
    const int cam   = blockIdx.z;
    const int pbase = blockIdx.x * 32;
    const int cbase = blockIdx.y * 32;
    const int tx = threadIdx.x, ty = threadIdx.y;

    const float* src = in  + (size_t)cam * CCH * PIX;
    float*       dst = out + (size_t)cam * PIX * CCH;

    #pragma unroll
    for (int j = 0; j < 4; ++j) {
        int c = cbase + ty + j * 8;
        tile[ty + j * 8][tx] =
            __builtin_nontemporal_load(&src[(size_t)c * PIX + (pbase + tx)]);
    }
    __syncthreads();
    #pragma unroll
    for (int j = 0; j < 4; ++j) {
        int p = pbase + ty + j * 8;
        dst[(size_t)p * CCH + (cbase + tx)] = tile[tx][ty + j * 8];
    }
}

// ---------------------------------------------------------------------------
// Kernel 2: LDS-staged gather. Block = 256 threads, QT=64 queries.
//  A) threads 0..63 resolve cam/scale/base-offset for one query each.
//     valid/points are single-use -> non-temporal loads.
//  B) 8 groups of 32 lanes: each group reads one query's 512B feature vector
//     as ONE coalesced 32-lane global_load_dwordx4 (each 64B line fetched
//     once, fully used) -> LDS, scale applied. imgT loads stay CACHED
//     (reused ~9.5x across blocks) - this is the data we protect in L2/L3.
//  C) lanes over q: float4 stores to out (c, q). out is 327 MB streaming,
//     single-use -> non-temporal stores so it does not evict imgT.
// LDS: 64*129*4 + 64*8 = 33.5 KB -> 4 blocks/CU, 16 waves/CU.
// ---------------------------------------------------------------------------
__global__ __launch_bounds__(256) void gather_lds_kernel(
    const float* __restrict__ imgT,     // (cam, y, x, c)
    const float* __restrict__ points,   // (cam, NQ, 2)
    const int*   __restrict__ valid,    // (cam, NQ) int32
    float*       __restrict__ out) {    // (c, NQ)
    __shared__ float feat[QT * LSTRIDE];
    __shared__ int   sbase[QT];
    __shared__ float sscale[QT];

    const int t     = threadIdx.x;
    const int qbase = blockIdx.x * QT;

    // ---- Phase A: resolve ----
    if (t < QT) {
        const int q = qbase + t;
        int sel = -1;
        #pragma unroll
        for (int cam = 0; cam < NCAM; ++cam)
            if (__builtin_nontemporal_load(&valid[(size_t)cam * NQ + q]) != 0)
                sel = cam;                                  // highest valid
        const int cam = (sel >= 0) ? sel : 0;
        sscale[t] = (sel >= 0) ? 1.0f : 0.0f;
        const f32x2 pt = __builtin_nontemporal_load(
            (const f32x2*)points + (size_t)cam * NQ + q);
        const int x = __float2int_rn(pt.x);   // RNE == jnp.round
        const int y = __float2int_rn(pt.y);
        sbase[t] = ((cam * IH + y) * IW + x) * CCH;   // word offset, < 2^31
    }
    __syncthreads();

    // ---- Phase B: coalesced 512B reads -> LDS (cached loads, want L3 hits) ----
    {
        const int grp  = t >> 5;      // 0..7
        const int lane = t & 31;
        #pragma unroll
        for (int i = 0; i < 8; ++i) {
            const int ql = i * 8 + grp;
            const float s = sscale[ql];
            const f32x4 v = *((const f32x4*)(imgT + sbase[ql]) + lane);
            const int w = ql * LSTRIDE + 4 * lane;
            feat[w + 0] = v.x * s;
            feat[w + 1] = v.y * s;
            feat[w + 2] = v.z * s;
            feat[w + 3] = v.w * s;
        }
    }
    __syncthreads();

    // ---- Phase C: LDS -> out, non-temporal float4 stores, lanes over q ----
    {
        const int l    = t & 63;
        const int wv   = t >> 6;      // wave id 0..3
        const int qq   = l & 15;      // q-quad 0..15
        const int csub = l >> 4;      // 0..3
        #pragma unroll
        for (int iter = 0; iter < 8; ++iter) {
            const int c    = iter * 16 + wv * 4 + csub;
            const int qoff = 4 * qq;
            f32x4 v;
            v.x = feat[(qoff + 0) * LSTRIDE + c];
            v.y = feat[(qoff + 1) * LSTRIDE + c];
            v.z = feat[(qoff + 2) * LSTRIDE + c];
            v.w = feat[(qoff + 3) * LSTRIDE + c];
            __builtin_nontemporal_store(
                v, (f32x4*)(out + (size_t)c * NQ + qbase + qoff));
        }
    }
}

// ---------------------------------------------------------------------------
// Fallback: direct gather from (cam, c, y, x) if workspace too small.
// ---------------------------------------------------------------------------
__global__ __launch_bounds__(256) void gather_direct_kernel(
    const float* __restrict__ img,
    const float* __restrict__ points,
    const int*   __restrict__ valid,
    float*       __restrict__ out) {
    const int q = blockIdx.x * 256 + threadIdx.x;

    int sel = -1;
    #pragma unroll
    for (int cam = 0; cam < NCAM; ++cam)
        if (valid[(size_t)cam * NQ + q] != 0) sel = cam;

    const float scale = (sel >= 0) ? 1.0f : 0.0f;
    const int cam = (sel >= 0) ? sel : 0;

    const float2 pt = ((const float2*)points)[(size_t)cam * NQ + q];
    const int x = __float2int_rn(pt.x);
    const int y = __float2int_rn(pt.y);

    const float* src = img + ((size_t)cam * CCH * IH + y) * IW + x;
    #pragma unroll 8
    for (int c = 0; c < CCH; ++c)
        out[(size_t)c * NQ + q] = src[(size_t)c * PIX] * scale;
}

extern "C" void kernel_launch(void* const* d_in, const int* in_sizes, int n_in,
                              void* d_out, int out_size, void* d_ws, size_t ws_size,
                              hipStream_t stream) {
    const float* img    = (const float*)d_in[0];
    const float* points = (const float*)d_in[1];
    const int*   valid  = (const int*)  d_in[2];
    float*       out    = (float*)d_out;

    const size_t need = (size_t)NCAM * CCH * IH * IW * sizeof(float);
    if (ws_size >= need) {
        float* imgT = (float*)d_ws;
        dim3 tb(32, 8, 1);
        dim3 tg(PIX / 32, CCH / 32, NCAM);
        transpose_kernel<<<tg, tb, 0, stream>>>(img, imgT);
        gather_lds_kernel<<<NQ / QT, 256, 0, stream>>>(imgT, points, valid, out);
    } else {
        gather_direct_kernel<<<NQ / 256, 256, 0, stream>>>(img, points, valid, out);
    }
}

// Round 3
// 416.223 us; speedup vs baseline: 1.0087x; 1.0087x over previous
//
#include <hip/hip_runtime.h>

#define NCAM 6
#define CCH  128
#define IH   64
#define IW   176
#define NQ   640000           // 200*200*16
#define PIX  (IH * IW)        // 11264 = 352*32
#define QT   32               // queries per block (R1: 64 -> 32 for occupancy)
#define LSTRIDE 129           // odd LDS stride: phase-C reads 2-way max (free)

typedef float f32x2 __attribute__((ext_vector_type(2)));
typedef float f32x4 __attribute__((ext_vector_type(4)));

// ---------------------------------------------------------------------------
// Kernel 1: transpose img_feats (cam, c, y, x) -> (cam, y, x, c). ~15 us.
// Source reads single-use -> non-temporal; keep L2/L3 for imgT (reused by
// the gather kernel).
// ---------------------------------------------------------------------------
__global__ __launch_bounds__(256) void transpose_kernel(
    const float* __restrict__ in, float* __restrict__ out) {
    __shared__ float tile[32][33];
    const int cam   = blockIdx.z;
    const int pbase = blockIdx.x * 32;
    const int cbase = blockIdx.y * 32;
    const int tx = threadIdx.x, ty = threadIdx.y;

    const float* src = in  + (size_t)cam * CCH * PIX;
    float*       dst = out + (size_t)cam * PIX * CCH;

    #pragma unroll
    for (int j = 0; j < 4; ++j) {
        int c = cbase + ty + j * 8;
        tile[ty + j * 8][tx] =
            __builtin_nontemporal_load(&src[(size_t)c * PIX + (pbase + tx)]);
    }
    __syncthreads();
    #pragma unroll
    for (int j = 0; j < 4; ++j) {
        int p = pbase + ty + j * 8;
        dst[(size_t)p * CCH + (cbase + tx)] = tile[tx][ty + j * 8];
    }
}

// ---------------------------------------------------------------------------
// Kernel 2: LDS-staged gather. Block = 256 threads, QT=32 queries.
// R1 theory (unmeasured in R2 - acquisition timeout; under test now):
// gather was latency-bound at 16/32 waves/CU (33.5 KB LDS -> 4 blocks/CU).
// QT=32 halves LDS to 16.8 KB -> 8 blocks/CU, 32 waves/CU (full occupancy),
// doubling outstanding scattered reads and halving per-barrier granularity.
//  A) threads 0..31 resolve cam/scale/base-offset (valid/points NT loads).
//  B) 8 groups of 32 lanes; each group, 4 iters: one coalesced 32-lane
//     global_load_dwordx4 = one query's 512B vector -> LDS (scaled).
//     imgT loads stay CACHED (the reused data we protect in L2/L3).
//  C) lanes over (qq, csub): 4 iters, f32x4 NT stores to out (c, q).
//     Bank math at QT=32/LSTRIDE=129: word = (4qq+j)*129 + iter*32 + wv*8
//     + csub -> bank = (4qq + csub + k) mod 32, qq in [0,8), csub in [0,8):
//     each bank hit by <=2 lanes -> 2-way = free.
// LDS: 32*129*4 + 32*8 = 16.8 KB -> 8 blocks/CU. __launch_bounds__(256,8)
// holds VGPR <= 64 for 8 waves/SIMD.
// ---------------------------------------------------------------------------
__global__ __launch_bounds__(256, 8) void gather_lds_kernel(
    const float* __restrict__ imgT,     // (cam, y, x, c)
    const float* __restrict__ points,   // (cam, NQ, 2)
    const int*   __restrict__ valid,    // (cam, NQ) int32
    float*       __restrict__ out) {    // (c, NQ)
    __shared__ float feat[QT * LSTRIDE];
    __shared__ int   sbase[QT];
    __shared__ float sscale[QT];

    const int t     = threadIdx.x;
    const int qbase = blockIdx.x * QT;

    // ---- Phase A: resolve ----
    if (t < QT) {
        const int q = qbase + t;
        int sel = -1;
        #pragma unroll
        for (int cam = 0; cam < NCAM; ++cam)
            if (__builtin_nontemporal_load(&valid[(size_t)cam * NQ + q]) != 0)
                sel = cam;                                  // highest valid
        const int cam = (sel >= 0) ? sel : 0;
        sscale[t] = (sel >= 0) ? 1.0f : 0.0f;
        const f32x2 pt = __builtin_nontemporal_load(
            (const f32x2*)points + (size_t)cam * NQ + q);
        const int x = __float2int_rn(pt.x);   // RNE == jnp.round
        const int y = __float2int_rn(pt.y);
        sbase[t] = ((cam * IH + y) * IW + x) * CCH;   // word offset, < 2^31
    }
    __syncthreads();

    // ---- Phase B: coalesced 512B reads -> LDS (cached loads, want L2/L3 hits) ----
    {
        const int grp  = t >> 5;      // 0..7
        const int lane = t & 31;
        #pragma unroll
        for (int i = 0; i < 4; ++i) {
            const int ql = i * 8 + grp;
            const float s = sscale[ql];
            const f32x4 v = *((const f32x4*)(imgT + sbase[ql]) + lane);
            const int w = ql * LSTRIDE + 4 * lane;
            feat[w + 0] = v.x * s;
            feat[w + 1] = v.y * s;
            feat[w + 2] = v.z * s;
            feat[w + 3] = v.w * s;
        }
    }
    __syncthreads();

    // ---- Phase C: LDS -> out, non-temporal float4 stores ----
    {
        const int l    = t & 63;
        const int wv   = t >> 6;      // wave id 0..3
        const int qq   = l & 7;       // q-quad 0..7
        const int csub = l >> 3;      // 0..7
        #pragma unroll
        for (int iter = 0; iter < 4; ++iter) {
            const int c    = iter * 32 + wv * 8 + csub;
            const int qoff = 4 * qq;
            f32x4 v;
            v.x = feat[(qoff + 0) * LSTRIDE + c];
            v.y = feat[(qoff + 1) * LSTRIDE + c];
            v.z = feat[(qoff + 2) * LSTRIDE + c];
            v.w = feat[(qoff + 3) * LSTRIDE + c];
            __builtin_nontemporal_store(
                v, (f32x4*)(out + (size_t)c * NQ + qbase + qoff));
        }
    }
}

// ---------------------------------------------------------------------------
// Fallback: direct gather from (cam, c, y, x) if workspace too small.
// ---------------------------------------------------------------------------
__global__ __launch_bounds__(256) void gather_direct_kernel(
    const float* __restrict__ img,
    const float* __restrict__ points,
    const int*   __restrict__ valid,
    float*       __restrict__ out) {
    const int q = blockIdx.x * 256 + threadIdx.x;

    int sel = -1;
    #pragma unroll
    for (int cam = 0; cam < NCAM; ++cam)
        if (valid[(size_t)cam * NQ + q] != 0) sel = cam;

    const float scale = (sel >= 0) ? 1.0f : 0.0f;
    const int cam = (sel >= 0) ? sel : 0;

    const float2 pt = ((const float2*)points)[(size_t)cam * NQ + q];
    const int x = __float2int_rn(pt.x);
    const int y = __float2int_rn(pt.y);

    const float* src = img + ((size_t)cam * CCH * IH + y) * IW + x;
    #pragma unroll 8
    for (int c = 0; c < CCH; ++c)
        out[(size_t)c * NQ + q] = src[(size_t)c * PIX] * scale;
}

extern "C" void kernel_launch(void* const* d_in, const int* in_sizes, int n_in,
                              void* d_out, int out_size, void* d_ws, size_t ws_size,
                              hipStream_t stream) {
    const float* img    = (const float*)d_in[0];
    const float* points = (const float*)d_in[1];
    const int*   valid  = (const int*)  d_in[2];
    float*       out    = (float*)d_out;

    const size_t need = (size_t)NCAM * CCH * IH * IW * sizeof(float);
    if (ws_size >= need) {
        float* imgT = (float*)d_ws;
        dim3 tb(32, 8, 1);
        dim3 tg(PIX / 32, CCH / 32, NCAM);
        transpose_kernel<<<tg, tb, 0, stream>>>(img, imgT);
        gather_lds_kernel<<<NQ / QT, 256, 0, stream>>>(imgT, points, valid, out);
    } else {
        gather_direct_kernel<<<NQ / 256, 256, 0, stream>>>(img, points, valid, out);
    }
}